// Round 1
// baseline (2233.448 us; speedup 1.0000x reference)
//
#include <hip/hip_runtime.h>
#include <cstddef>

#define S 2048
#define Dm 2048
#define NH 32
#define NG 8
#define HD 64

// ---------------- GEMM: C[M,N] = A[M,K] * B[N,K]^T (fp32, 64x64 tile) ----------------
__global__ __launch_bounds__(256) void gemm_bt(const float* __restrict__ A,
                                               const float* __restrict__ B,
                                               float* __restrict__ C,
                                               int M, int N, int K) {
  __shared__ float As[16][65];   // [k][m], stride 65 -> conflict-free
  __shared__ float Bs[16][65];   // [k][n]
  const int tid = threadIdx.x;
  const int row0 = blockIdx.y * 64, col0 = blockIdx.x * 64;
  const int tx = tid & 15, ty = tid >> 4;
  float acc[4][4];
#pragma unroll
  for (int i = 0; i < 4; i++)
#pragma unroll
    for (int j = 0; j < 4; j++) acc[i][j] = 0.f;

  for (int k0 = 0; k0 < K; k0 += 16) {
#pragma unroll
    for (int i = 0; i < 4; i++) {
      int idx = tid + i * 256;          // 0..1023 covers 64 rows x 16 k
      int m = idx >> 4, kk = idx & 15;
      As[kk][m] = A[(size_t)(row0 + m) * K + k0 + kk];
      Bs[kk][m] = B[(size_t)(col0 + m) * K + k0 + kk];
    }
    __syncthreads();
#pragma unroll
    for (int kk = 0; kk < 16; kk++) {
      float a[4], b[4];
#pragma unroll
      for (int i = 0; i < 4; i++) a[i] = As[kk][ty * 4 + i];
#pragma unroll
      for (int j = 0; j < 4; j++) b[j] = Bs[kk][tx * 4 + j];
#pragma unroll
      for (int i = 0; i < 4; i++)
#pragma unroll
        for (int j = 0; j < 4; j++) acc[i][j] += a[i] * b[j];
    }
    __syncthreads();
  }
#pragma unroll
  for (int i = 0; i < 4; i++)
#pragma unroll
    for (int j = 0; j < 4; j++)
      C[(size_t)(row0 + ty * 4 + i) * N + col0 + tx * 4 + j] = acc[i][j];
}

// ---------------- RoPE (in place), layout T[s][h*HD + d] ----------------
// out[d]    = t[d]*cos[d]    - t[d+32]*sin[d]       (d < 32)
// out[d+32] = t[d+32]*cos[d+32] + t[d]*sin[d+32]
__global__ __launch_bounds__(256) void rope_kernel(float* __restrict__ T,
                                                   const float* __restrict__ cosv,
                                                   const float* __restrict__ sinv,
                                                   int nheads) {
  int i = blockIdx.x * 256 + threadIdx.x;   // over S*nheads*32
  int d = i & 31;
  int h = (i >> 5) % nheads;
  int s = i / (32 * nheads);
  float* row = T + ((size_t)s * nheads + h) * HD;
  float c1 = cosv[s * HD + d];
  float s1 = sinv[s * HD + d];
  float c2 = cosv[s * HD + d + 32];
  float s2 = sinv[s * HD + d + 32];
  float t1 = row[d], t2 = row[d + 32];
  row[d]      = t1 * c1 - t2 * s1;
  row[d + 32] = t2 * c2 + t1 * s2;
}

// ---------------- causal GQA flash attention ----------------
// grid (S/32, NH); block 256 = 4 waves; wave w handles q rows qb*32 + w*8 .. +7
// Q[s][h*64+d], K/V[s][g*64+d]; out O[s][h*64+d]
__global__ __launch_bounds__(256) void flash_attn(const float* __restrict__ Qp,
                                                  const float* __restrict__ Kp,
                                                  const float* __restrict__ Vp,
                                                  float* __restrict__ Op) {
  __shared__ __align__(16) float Ks[64][68];   // [key][d], stride 68 (b128-aligned)
  __shared__ __align__(16) float Vt[64][68];   // [d][key] transposed
  __shared__ __align__(16) float Qs[32][68];   // [row][d], pre-scaled by 1/8
  __shared__ __align__(16) float Ps[4][8][64]; // per-wave P tile [row][key]

  const int tid = threadIdx.x;
  const int wave = tid >> 6, lane = tid & 63;
  const int h = blockIdx.y;
  const int g = h >> 2;               // GS = 4
  const int qrow0 = blockIdx.x * 32;

  // stage Q (scaled by 1/sqrt(HD) = 0.125)
  for (int i = tid; i < 32 * 16; i += 256) {
    int r = i >> 4, d4 = i & 15;
    float4 q4 = ((const float4*)Qp)[(size_t)(qrow0 + r) * 512 + h * 16 + d4];
    Qs[r][d4 * 4 + 0] = q4.x * 0.125f;
    Qs[r][d4 * 4 + 1] = q4.y * 0.125f;
    Qs[r][d4 * 4 + 2] = q4.z * 0.125f;
    Qs[r][d4 * 4 + 3] = q4.w * 0.125f;
  }

  float m_i[8], l_i[8], acc[8];
#pragma unroll
  for (int r = 0; r < 8; r++) { m_i[r] = -__builtin_inff(); l_i[r] = 0.f; acc[r] = 0.f; }

  const int ntiles = (qrow0 + 31) / 64 + 1;   // causal: only tiles with keys <= max q row
  for (int t = 0; t < ntiles; t++) {
    const int k0 = t * 64;
    __syncthreads();   // protects Qs (t=0) and prev-iter Ks/Vt/Ps reads
    for (int i = tid; i < 64 * 16; i += 256) {
      int k = i >> 4, d4 = i & 15;
      float4 k4 = ((const float4*)Kp)[(size_t)(k0 + k) * 128 + g * 16 + d4];
      *(float4*)&Ks[k][d4 * 4] = k4;
      float4 v4 = ((const float4*)Vp)[(size_t)(k0 + k) * 128 + g * 16 + d4];
      Vt[d4 * 4 + 0][k] = v4.x;
      Vt[d4 * 4 + 1][k] = v4.y;
      Vt[d4 * 4 + 2][k] = v4.z;
      Vt[d4 * 4 + 3][k] = v4.w;
    }
    __syncthreads();

    // scores: lane = key j of this tile
    float sc[8];
#pragma unroll
    for (int r = 0; r < 8; r++) sc[r] = 0.f;
#pragma unroll
    for (int d4 = 0; d4 < 16; d4++) {
      float4 kk = *(const float4*)&Ks[lane][d4 * 4];
#pragma unroll
      for (int r = 0; r < 8; r++) {
        float4 qq = *(const float4*)&Qs[wave * 8 + r][d4 * 4];  // broadcast read
        sc[r] += kk.x * qq.x + kk.y * qq.y + kk.z * qq.z + kk.w * qq.w;
      }
    }

    const int kidx = k0 + lane;
#pragma unroll
    for (int r = 0; r < 8; r++) {
      const int qrow = qrow0 + wave * 8 + r;
      float sv = (kidx <= qrow) ? sc[r] : -__builtin_inff();
      float mt = sv;
#pragma unroll
      for (int off = 32; off > 0; off >>= 1) mt = fmaxf(mt, __shfl_xor(mt, off));
      float mnew = fmaxf(m_i[r], mt);       // tile 0 always has a valid key -> finite
      float p = __expf(sv - mnew);
      float alpha = __expf(m_i[r] - mnew);
      m_i[r] = mnew;
      float ps = p;
#pragma unroll
      for (int off = 32; off > 0; off >>= 1) ps += __shfl_xor(ps, off);
      l_i[r] = l_i[r] * alpha + ps;
      acc[r] *= alpha;
      Ps[wave][r][lane] = p;
    }
    __syncthreads();   // Ps write -> broadcast read (and aligns waves)

    // PV: lane = dim d; acc[r] += sum_j P[r][j] * V[j][d]
#pragma unroll
    for (int j4 = 0; j4 < 16; j4++) {
      float4 vv = *(const float4*)&Vt[lane][j4 * 4];
#pragma unroll
      for (int r = 0; r < 8; r++) {
        float4 pp = *(const float4*)&Ps[wave][r][j4 * 4];  // broadcast read
        acc[r] += pp.x * vv.x + pp.y * vv.y + pp.z * vv.z + pp.w * vv.w;
      }
    }
  }

#pragma unroll
  for (int r = 0; r < 8; r++) {
    const int qrow = qrow0 + wave * 8 + r;
    Op[(size_t)qrow * 2048 + h * 64 + lane] = acc[r] / l_i[r];
  }
}

extern "C" void kernel_launch(void* const* d_in, const int* in_sizes, int n_in,
                              void* d_out, int out_size, void* d_ws, size_t ws_size,
                              hipStream_t stream) {
  const float* x    = (const float*)d_in[0];
  // d_in[1] = mask: triu(k=1) causal -> computed analytically, never read
  const float* cosv = (const float*)d_in[2];
  const float* sinv = (const float*)d_in[3];
  const float* Wq   = (const float*)d_in[4];
  const float* Wk   = (const float*)d_in[5];
  const float* Wv   = (const float*)d_in[6];
  const float* Wo   = (const float*)d_in[7];
  float* out = (float*)d_out;

  float* ws = (float*)d_ws;
  float* Qb = ws;                                  // S*2048 = 16.8 MB
  float* Kb = Qb + (size_t)S * NH * HD;            // S*512  =  4.2 MB
  float* Vb = Kb + (size_t)S * NG * HD;            // S*512  =  4.2 MB
  float* Ab = Vb + (size_t)S * NG * HD;            // S*2048 = 16.8 MB   (total ~42 MB)

  dim3 blk(256);
  gemm_bt<<<dim3(32, 32), blk, 0, stream>>>(x, Wq, Qb, S, NH * HD, Dm);
  gemm_bt<<<dim3(8, 32),  blk, 0, stream>>>(x, Wk, Kb, S, NG * HD, Dm);
  gemm_bt<<<dim3(8, 32),  blk, 0, stream>>>(x, Wv, Vb, S, NG * HD, Dm);
  rope_kernel<<<(S * NH * 32) / 256, blk, 0, stream>>>(Qb, cosv, sinv, NH);
  rope_kernel<<<(S * NG * 32) / 256, blk, 0, stream>>>(Kb, cosv, sinv, NG);
  flash_attn<<<dim3(S / 32, NH), blk, 0, stream>>>(Qb, Kb, Vb, Ab);
  gemm_bt<<<dim3(32, 32), blk, 0, stream>>>(Ab, Wo, out, S, NH * HD, NH * HD);
}

// Round 2
// 394.001 us; speedup vs baseline: 5.6686x; 5.6686x over previous
//
#include <hip/hip_runtime.h>
#include <cstddef>
#include <cstdint>

#define S 2048
#define Dm 2048
#define NH 32
#define NG 8
#define HD 64

typedef __attribute__((ext_vector_type(8))) short bf16x8;
typedef __attribute__((ext_vector_type(4))) float f32x4;

__device__ __forceinline__ unsigned short f2bf(float f) {
  unsigned int u = __builtin_bit_cast(unsigned int, f);
  u = (u + 0x7fffu + ((u >> 16) & 1u)) >> 16;
  return (unsigned short)u;
}
__device__ __forceinline__ float bf2f(unsigned short h) {
  unsigned int u = ((unsigned int)h) << 16;
  return __builtin_bit_cast(float, u);
}

// ---------------- fp32 -> bf16 convert, 4 elems/thread ----------------
__global__ __launch_bounds__(256) void cvt4(const float* __restrict__ in,
                                            unsigned short* __restrict__ out,
                                            int n4) {
  int i = blockIdx.x * 256 + threadIdx.x;
  if (i >= n4) return;
  float4 v = ((const float4*)in)[i];
  ushort4 o;
  o.x = f2bf(v.x); o.y = f2bf(v.y); o.z = f2bf(v.z); o.w = f2bf(v.w);
  ((ushort4*)out)[i] = o;
}

// ---------------- bf16 MFMA GEMM: C[M,N] = A[M,K] * B[N,K]^T ----------------
// 128x128 tile, BK=32, 4 waves of 64x64 (4x4 of 16x16x32 mfma).
// Output: Cf (fp32) if non-null, else Cb (bf16).
__global__ __launch_bounds__(256) void gemm_bf16(const unsigned short* __restrict__ A,
                                                 const unsigned short* __restrict__ B,
                                                 float* __restrict__ Cf,
                                                 unsigned short* __restrict__ Cb,
                                                 int M, int N, int K) {
  __shared__ __align__(16) unsigned short As[128 * 32];
  __shared__ __align__(16) unsigned short Bs[128 * 32];
  const int tid = threadIdx.x;
  const int lane = tid & 63, wave = tid >> 6;
  const int row0 = blockIdx.y * 128, col0 = blockIdx.x * 128;
  const int wr = (wave >> 1) * 64, wc = (wave & 1) * 64;

  f32x4 acc[4][4];
#pragma unroll
  for (int i = 0; i < 4; i++)
#pragma unroll
    for (int j = 0; j < 4; j++) acc[i][j] = (f32x4){0.f, 0.f, 0.f, 0.f};

  const int srow = tid >> 2;            // 0..63
  const int schunk = (tid & 3) * 8;     // ushort offset in row of 32
  const int fr = lane & 15, fk = (lane >> 4) * 8;

  for (int k0 = 0; k0 < K; k0 += 32) {
    *(bf16x8*)&As[srow * 32 + schunk]        = *(const bf16x8*)&A[(size_t)(row0 + srow) * K + k0 + schunk];
    *(bf16x8*)&As[(srow + 64) * 32 + schunk] = *(const bf16x8*)&A[(size_t)(row0 + srow + 64) * K + k0 + schunk];
    *(bf16x8*)&Bs[srow * 32 + schunk]        = *(const bf16x8*)&B[(size_t)(col0 + srow) * K + k0 + schunk];
    *(bf16x8*)&Bs[(srow + 64) * 32 + schunk] = *(const bf16x8*)&B[(size_t)(col0 + srow + 64) * K + k0 + schunk];
    __syncthreads();
    bf16x8 af[4], bfr[4];
#pragma unroll
    for (int i = 0; i < 4; i++) af[i]  = *(const bf16x8*)&As[(wr + i * 16 + fr) * 32 + fk];
#pragma unroll
    for (int j = 0; j < 4; j++) bfr[j] = *(const bf16x8*)&Bs[(wc + j * 16 + fr) * 32 + fk];
#pragma unroll
    for (int i = 0; i < 4; i++)
#pragma unroll
      for (int j = 0; j < 4; j++)
        acc[i][j] = __builtin_amdgcn_mfma_f32_16x16x32_bf16(af[i], bfr[j], acc[i][j], 0, 0, 0);
    __syncthreads();
  }

  // C/D layout: col = lane&15, row = (lane>>4)*4 + reg
  const int cc = lane & 15, cr = (lane >> 4) * 4;
#pragma unroll
  for (int i = 0; i < 4; i++)
#pragma unroll
    for (int j = 0; j < 4; j++) {
      int gc = col0 + wc + j * 16 + cc;
#pragma unroll
      for (int r = 0; r < 4; r++) {
        int gr = row0 + wr + i * 16 + cr + r;
        if (Cf) Cf[(size_t)gr * N + gc] = acc[i][j][r];
        else    Cb[(size_t)gr * N + gc] = f2bf(acc[i][j][r]);
      }
    }
}

// ---------------- RoPE in place on bf16 QKV buffer [s][3072] ----------------
// Q cols h*64 (h<32), K cols 2048 + g*64 (g<8); V untouched.
__global__ __launch_bounds__(256) void rope_bf16(unsigned short* __restrict__ QKV,
                                                 const float* __restrict__ cosv,
                                                 const float* __restrict__ sinv) {
  int i = blockIdx.x * 256 + threadIdx.x;    // over S*40*32
  int d = i & 31;
  int hh = (i >> 5) % 40;
  int s = i / (32 * 40);
  int col = (hh < 32) ? hh * 64 : 2048 + (hh - 32) * 64;
  unsigned short* row = QKV + (size_t)s * 3072 + col;
  float c1 = cosv[s * 64 + d],      s1 = sinv[s * 64 + d];
  float c2 = cosv[s * 64 + d + 32], s2 = sinv[s * 64 + d + 32];
  float t1 = bf2f(row[d]), t2 = bf2f(row[d + 32]);
  row[d]      = f2bf(t1 * c1 - t2 * s1);
  row[d + 32] = f2bf(t2 * c2 + t1 * s2);
}

// ---------------- MFMA causal GQA flash attention ----------------
// grid (S/64, NH); block 256 = 4 waves; wave w: q rows qb + w*16 .. +15
// QKV bf16 [s][3072]: Q at h*64, K at 2048+g*64, V at 2560+g*64. Out Ob bf16 [s][2048].
__global__ __launch_bounds__(256) void flash_mfma(const unsigned short* __restrict__ QKV,
                                                  unsigned short* __restrict__ Ob) {
  __shared__ __align__(16) unsigned short Ks[64 * 64];   // [key][dim]
  __shared__ __align__(16) unsigned short Vt[64 * 72];   // [dim][key], pad 72
  __shared__ __align__(16) unsigned short Pl[4 * 16 * 64]; // per-wave P [16 q][64 key]

  const int tid = threadIdx.x;
  const int lane = tid & 63, wave = tid >> 6;
  const int h = blockIdx.y, g = h >> 2;
  const int qb = blockIdx.x * 64;
  const int m15 = lane & 15, q4 = lane >> 4;

  // Q fragments (A-layout): row = qb + wave*16 + (lane&15), k = q4*8 + j (+32 for f1)
  const size_t qrow = (size_t)(qb + wave * 16 + m15) * 3072 + h * 64;
  const bf16x8 qf0 = *(const bf16x8*)&QKV[qrow + q4 * 8];
  const bf16x8 qf1 = *(const bf16x8*)&QKV[qrow + 32 + q4 * 8];

  f32x4 accO[4];
  float m_i[4], l_i[4];
#pragma unroll
  for (int v = 0; v < 4; v++) accO[v] = (f32x4){0.f, 0.f, 0.f, 0.f};
#pragma unroll
  for (int r = 0; r < 4; r++) { m_i[r] = -1e30f; l_i[r] = 0.f; }

  const int tmax = blockIdx.x;
  for (int t = 0; t <= tmax; t++) {
    const int k0 = t * 64;
    __syncthreads();   // protect prior-iter Ks/Vt reads before restaging
    // stage Ks [64][64]: 512 chunks of 8 ushorts, 2 per thread (coalesced)
#pragma unroll
    for (int i = 0; i < 2; i++) {
      int c = tid + i * 256;
      int r = c >> 3, o = (c & 7) * 8;
      *(bf16x8*)&Ks[r * 64 + o] = *(const bf16x8*)&QKV[(size_t)(k0 + r) * 3072 + 2048 + g * 64 + o];
    }
    // stage Vt [dim][key]: lane = key, wave covers dims wave*16..+15
    {
      const size_t vrow = (size_t)(k0 + lane) * 3072 + 2560 + g * 64 + wave * 16;
      bf16x8 v0 = *(const bf16x8*)&QKV[vrow];
      bf16x8 v1 = *(const bf16x8*)&QKV[vrow + 8];
#pragma unroll
      for (int j = 0; j < 8; j++) {
        Vt[(wave * 16 + j) * 72 + lane]     = (unsigned short)v0[j];
        Vt[(wave * 16 + 8 + j) * 72 + lane] = (unsigned short)v1[j];
      }
    }
    __syncthreads();

    // QK^T: S[16 q][64 key] per wave = 4 key-tiles x (2 k-steps)
    f32x4 sc[4];
#pragma unroll
    for (int kt = 0; kt < 4; kt++) {
      bf16x8 kf0 = *(const bf16x8*)&Ks[(kt * 16 + m15) * 64 + q4 * 8];
      bf16x8 kf1 = *(const bf16x8*)&Ks[(kt * 16 + m15) * 64 + 32 + q4 * 8];
      sc[kt] = (f32x4){0.f, 0.f, 0.f, 0.f};
      sc[kt] = __builtin_amdgcn_mfma_f32_16x16x32_bf16(qf0, kf0, sc[kt], 0, 0, 0);
      sc[kt] = __builtin_amdgcn_mfma_f32_16x16x32_bf16(qf1, kf1, sc[kt], 0, 0, 0);
    }

    // scale + causal mask (diagonal tile only)
#pragma unroll
    for (int kt = 0; kt < 4; kt++)
#pragma unroll
      for (int r = 0; r < 4; r++) sc[kt][r] *= 0.125f;
    if (t == tmax) {
#pragma unroll
      for (int kt = 0; kt < 4; kt++) {
        int key = k0 + kt * 16 + m15;
#pragma unroll
        for (int r = 0; r < 4; r++) {
          int qr = qb + wave * 16 + q4 * 4 + r;
          if (key > qr) sc[kt][r] = -1e30f;
        }
      }
    }

    // online softmax per C-layout row r (q = q4*4 + r); reduce over 16 lanes
#pragma unroll
    for (int r = 0; r < 4; r++) {
      float mt = fmaxf(fmaxf(sc[0][r], sc[1][r]), fmaxf(sc[2][r], sc[3][r]));
#pragma unroll
      for (int off = 1; off < 16; off <<= 1) mt = fmaxf(mt, __shfl_xor(mt, off));
      float mnew = fmaxf(m_i[r], mt);
      float alpha = __expf(m_i[r] - mnew);
      m_i[r] = mnew;
      float rs = 0.f;
#pragma unroll
      for (int kt = 0; kt < 4; kt++) {
        float p = __expf(sc[kt][r] - mnew);
        sc[kt][r] = p;
        rs += p;
      }
#pragma unroll
      for (int off = 1; off < 16; off <<= 1) rs += __shfl_xor(rs, off);
      l_i[r] = l_i[r] * alpha + rs;
#pragma unroll
      for (int v = 0; v < 4; v++) accO[v][r] *= alpha;
    }

    // P (C-layout) -> LDS -> A-layout fragments (per-wave region, no barrier needed)
#pragma unroll
    for (int kt = 0; kt < 4; kt++)
#pragma unroll
      for (int r = 0; r < 4; r++)
        Pl[wave * 1024 + (q4 * 4 + r) * 64 + kt * 16 + m15] = f2bf(sc[kt][r]);
    bf16x8 pf0 = *(const bf16x8*)&Pl[wave * 1024 + m15 * 64 + q4 * 8];
    bf16x8 pf1 = *(const bf16x8*)&Pl[wave * 1024 + m15 * 64 + 32 + q4 * 8];

    // PV: O[16 q][64 dim] += P[16][64] * V[64 key][64 dim]  (B = Vt[dim][key])
#pragma unroll
    for (int vt = 0; vt < 4; vt++) {
      bf16x8 vf0 = *(const bf16x8*)&Vt[(vt * 16 + m15) * 72 + q4 * 8];
      bf16x8 vf1 = *(const bf16x8*)&Vt[(vt * 16 + m15) * 72 + 32 + q4 * 8];
      accO[vt] = __builtin_amdgcn_mfma_f32_16x16x32_bf16(pf0, vf0, accO[vt], 0, 0, 0);
      accO[vt] = __builtin_amdgcn_mfma_f32_16x16x32_bf16(pf1, vf1, accO[vt], 0, 0, 0);
    }
  }

  // epilogue: O/l -> Ob bf16 [s][2048]
#pragma unroll
  for (int vt = 0; vt < 4; vt++)
#pragma unroll
    for (int r = 0; r < 4; r++) {
      int row = qb + wave * 16 + q4 * 4 + r;
      int col = h * 64 + vt * 16 + m15;
      Ob[(size_t)row * 2048 + col] = f2bf(accO[vt][r] / l_i[r]);
    }
}

extern "C" void kernel_launch(void* const* d_in, const int* in_sizes, int n_in,
                              void* d_out, int out_size, void* d_ws, size_t ws_size,
                              hipStream_t stream) {
  const float* x    = (const float*)d_in[0];
  // d_in[1] = mask: causal triu(k=1), computed analytically
  const float* cosv = (const float*)d_in[2];
  const float* sinv = (const float*)d_in[3];
  const float* Wq   = (const float*)d_in[4];
  const float* Wk   = (const float*)d_in[5];
  const float* Wv   = (const float*)d_in[6];
  const float* Wo   = (const float*)d_in[7];
  float* out = (float*)d_out;

  unsigned short* xb   = (unsigned short*)d_ws;            // 4.19M ush (8.4 MB); later reused as Ob
  unsigned short* Wcat = xb + (size_t)2048 * 2048;         // 6.29M ush (12.6 MB); later reused as Wo_bf
  unsigned short* QKV  = Wcat + (size_t)3072 * 2048;       // 6.29M ush (12.6 MB)

  dim3 blk(256);
  // convert inputs to bf16
  cvt4<<<4096, blk, 0, stream>>>(x,  xb,                            (2048 * 2048) / 4);
  cvt4<<<4096, blk, 0, stream>>>(Wq, Wcat,                          (2048 * 2048) / 4);
  cvt4<<<1024, blk, 0, stream>>>(Wk, Wcat + (size_t)2048 * 2048,    (512 * 2048) / 4);
  cvt4<<<1024, blk, 0, stream>>>(Wv, Wcat + (size_t)2560 * 2048,    (512 * 2048) / 4);
  // fused QKV projection: [2048,3072] = xb[2048,2048] @ Wcat[3072,2048]^T -> bf16
  gemm_bf16<<<dim3(24, 16), blk, 0, stream>>>(xb, Wcat, nullptr, QKV, 2048, 3072, 2048);
  // Wo -> bf16 (reuses Wcat space; stream order makes this safe)
  cvt4<<<4096, blk, 0, stream>>>(Wo, Wcat, (2048 * 2048) / 4);
  // RoPE on Q and K halves of QKV
  rope_bf16<<<(2048 * 40 * 32) / 256, blk, 0, stream>>>(QKV, cosv, sinv);
  // flash attention -> Ob (reuses xb space)
  flash_mfma<<<dim3(32, 32), blk, 0, stream>>>(QKV, xb);
  // output projection: out = Ob @ Wo^T (fp32 out)
  gemm_bf16<<<dim3(16, 16), blk, 0, stream>>>(xb, Wcat, out, nullptr, 2048, 2048, 2048);
}

// Round 3
// 357.165 us; speedup vs baseline: 6.2533x; 1.1031x over previous
//
#include <hip/hip_runtime.h>
#include <cstddef>
#include <cstdint>

#define S 2048
#define Dm 2048
#define NH 32
#define NG 8
#define HD 64

typedef __attribute__((ext_vector_type(8))) short bf16x8;
typedef __attribute__((ext_vector_type(4))) float f32x4;

__device__ __forceinline__ unsigned short f2bf(float f) {
  unsigned int u = __builtin_bit_cast(unsigned int, f);
  u = (u + 0x7fffu + ((u >> 16) & 1u)) >> 16;
  return (unsigned short)u;
}
__device__ __forceinline__ float bf2f(unsigned short h) {
  unsigned int u = ((unsigned int)h) << 16;
  return __builtin_bit_cast(float, u);
}
// async global->LDS, 16B per lane; lds ptr: each lane passes base + lane*16
__device__ __forceinline__ void gl_lds16(const unsigned short* g, unsigned short* l) {
  __builtin_amdgcn_global_load_lds(
      (const __attribute__((address_space(1))) unsigned int*)g,
      (__attribute__((address_space(3))) unsigned int*)l, 16, 0, 0);
}

// ---------------- fp32 -> bf16 convert, 4 elems/thread ----------------
__global__ __launch_bounds__(256) void cvt4(const float* __restrict__ in,
                                            unsigned short* __restrict__ out,
                                            int n4) {
  int i = blockIdx.x * 256 + threadIdx.x;
  if (i >= n4) return;
  float4 v = ((const float4*)in)[i];
  ushort4 o;
  o.x = f2bf(v.x); o.y = f2bf(v.y); o.z = f2bf(v.z); o.w = f2bf(v.w);
  ((ushort4*)out)[i] = o;
}

// ---------------- bf16 MFMA GEMM: C[M,N] = A[M,K] * B[N,K]^T ----------------
// 128x128 tile, BK=32, global_load_lds staging (m97 structure).
// Cols >= 2560 with VtOut set are written transposed to VtOut[(col-2560)*2048+row].
__global__ __launch_bounds__(256) void gemm_bf16(const unsigned short* __restrict__ A,
                                                 const unsigned short* __restrict__ B,
                                                 float* __restrict__ Cf,
                                                 unsigned short* __restrict__ Cb,
                                                 unsigned short* __restrict__ VtOut,
                                                 int M, int N, int K) {
  __shared__ __align__(16) unsigned short As[128 * 32];
  __shared__ __align__(16) unsigned short Bs[128 * 32];
  const int tid = threadIdx.x;
  const int lane = tid & 63, wave = tid >> 6;
  const int row0 = blockIdx.y * 128, col0 = blockIdx.x * 128;
  const int wr = (wave >> 1) * 64, wc = (wave & 1) * 64;

  f32x4 acc[4][4];
#pragma unroll
  for (int i = 0; i < 4; i++)
#pragma unroll
    for (int j = 0; j < 4; j++) acc[i][j] = (f32x4){0.f, 0.f, 0.f, 0.f};

  // staging chunks: 512 chunks of 16B per matrix; chunk c -> row c>>2, col (c&3)*8
  const int c0 = wave * 128 + lane, c1 = c0 + 64;
  const int rA0 = c0 >> 2, o0 = (c0 & 3) * 8;
  const int rA1 = c1 >> 2, o1 = (c1 & 3) * 8;
  const int fr = lane & 15, fk = (lane >> 4) * 8;

  for (int k0 = 0; k0 < K; k0 += 32) {
    gl_lds16(&A[(size_t)(row0 + rA0) * K + k0 + o0], &As[c0 * 8]);
    gl_lds16(&A[(size_t)(row0 + rA1) * K + k0 + o1], &As[c1 * 8]);
    gl_lds16(&B[(size_t)(col0 + rA0) * K + k0 + o0], &Bs[c0 * 8]);
    gl_lds16(&B[(size_t)(col0 + rA1) * K + k0 + o1], &Bs[c1 * 8]);
    __syncthreads();
    bf16x8 af[4], bfr[4];
#pragma unroll
    for (int i = 0; i < 4; i++) af[i]  = *(const bf16x8*)&As[(wr + i * 16 + fr) * 32 + fk];
#pragma unroll
    for (int j = 0; j < 4; j++) bfr[j] = *(const bf16x8*)&Bs[(wc + j * 16 + fr) * 32 + fk];
#pragma unroll
    for (int i = 0; i < 4; i++)
#pragma unroll
      for (int j = 0; j < 4; j++)
        acc[i][j] = __builtin_amdgcn_mfma_f32_16x16x32_bf16(af[i], bfr[j], acc[i][j], 0, 0, 0);
    __syncthreads();
  }

  // C/D layout: col = lane&15, row = (lane>>4)*4 + reg
  const int cc = lane & 15, cr = (lane >> 4) * 4;
  const bool vmode = (VtOut != nullptr) && (col0 >= 2560);
#pragma unroll
  for (int i = 0; i < 4; i++)
#pragma unroll
    for (int j = 0; j < 4; j++) {
      int gc = col0 + wc + j * 16 + cc;
#pragma unroll
      for (int r = 0; r < 4; r++) {
        int gr = row0 + wr + i * 16 + cr + r;
        if (vmode)       VtOut[(size_t)(gc - 2560) * 2048 + gr] = f2bf(acc[i][j][r]);
        else if (Cb)     Cb[(size_t)gr * N + gc] = f2bf(acc[i][j][r]);
        else             Cf[(size_t)gr * N + gc] = acc[i][j][r];
      }
    }
}

// ---------------- RoPE in place on bf16 QKV buffer [s][3072] ----------------
// Q cols h*64 (h<32, scaled by 1/sqrt(HD)), K cols 2048 + g*64; V untouched.
__global__ __launch_bounds__(256) void rope_bf16(unsigned short* __restrict__ QKV,
                                                 const float* __restrict__ cosv,
                                                 const float* __restrict__ sinv) {
  int i = blockIdx.x * 256 + threadIdx.x;    // over S*40*32
  int d = i & 31;
  int hh = (i >> 5) % 40;
  int s = i / (32 * 40);
  float sc = (hh < 32) ? 0.125f : 1.0f;      // fold 1/sqrt(64) into Q
  int col = (hh < 32) ? hh * 64 : 2048 + (hh - 32) * 64;
  unsigned short* row = QKV + (size_t)s * 3072 + col;
  float c1 = cosv[s * 64 + d],      s1 = sinv[s * 64 + d];
  float c2 = cosv[s * 64 + d + 32], s2 = sinv[s * 64 + d + 32];
  float t1 = bf2f(row[d]), t2 = bf2f(row[d + 32]);
  row[d]      = f2bf((t1 * c1 - t2 * s1) * sc);
  row[d + 32] = f2bf((t2 * c2 + t1 * s2) * sc);
}

// ---------------- MFMA causal GQA flash attention ----------------
// grid (16, NH); block 256 = 4 waves. qb = reversed bx * 128 (heavy blocks first).
// Wave w owns frag0 rows qb+w*16.. and frag1 rows qb+64+w*16.. (equal causal extent).
// K from QKV [s][3072] at 2048+g*64; V from Vt_g [g*64+d][s]; out Ob bf16 [s][2048].
// LDS tiles XOR-swizzled at 16B granularity: phys_chunk = log_chunk ^ (row&7).
__global__ __launch_bounds__(256) void flash_mfma(const unsigned short* __restrict__ QKV,
                                                  const unsigned short* __restrict__ Vt_g,
                                                  unsigned short* __restrict__ Ob) {
  __shared__ __align__(16) unsigned short Ks[64 * 64];
  __shared__ __align__(16) unsigned short Vs[64 * 64];
  __shared__ __align__(16) unsigned short Pl[4 * 16 * 72];

  const int tid = threadIdx.x;
  const int lane = tid & 63, wave = tid >> 6;
  const int h = blockIdx.y, g = h >> 2;
  const int bxr = gridDim.x - 1 - blockIdx.x;
  const int qb = bxr * 128;
  const int m15 = lane & 15, q4 = lane >> 4;

  // Q fragments (A-layout): row = m15, k = q4*8 + j
  bf16x8 qf[2][2];
#pragma unroll
  for (int f = 0; f < 2; f++) {
    const size_t qrow = (size_t)(qb + f * 64 + wave * 16 + m15) * 3072 + h * 64;
    qf[f][0] = *(const bf16x8*)&QKV[qrow + q4 * 8];
    qf[f][1] = *(const bf16x8*)&QKV[qrow + 32 + q4 * 8];
  }

  f32x4 accO[2][4];
  float m_i[2][4], l_i[2][4];
#pragma unroll
  for (int f = 0; f < 2; f++)
#pragma unroll
    for (int v = 0; v < 4; v++) accO[f][v] = (f32x4){0.f, 0.f, 0.f, 0.f};
#pragma unroll
  for (int f = 0; f < 2; f++)
#pragma unroll
    for (int r = 0; r < 4; r++) { m_i[f][r] = -1e30f; l_i[f][r] = 0.f; }

  // staging chunk indices (512 chunks of 16B; row = p>>3, swizzled col)
  const int p0 = wave * 128 + lane, p1 = p0 + 64;
  const int sr0 = p0 >> 3, so0 = ((p0 & 7) ^ (sr0 & 7)) * 8;
  const int sr1 = p1 >> 3, so1 = ((p1 & 7) ^ (sr1 & 7)) * 8;

  const int ntiles = 2 * bxr + 2;
  for (int t = 0; t < ntiles; t++) {
    const int k0 = t * 64;
    gl_lds16(&QKV[(size_t)(k0 + sr0) * 3072 + 2048 + g * 64 + so0], &Ks[p0 * 8]);
    gl_lds16(&QKV[(size_t)(k0 + sr1) * 3072 + 2048 + g * 64 + so1], &Ks[p1 * 8]);
    gl_lds16(&Vt_g[(size_t)(g * 64 + sr0) * 2048 + k0 + so0], &Vs[p0 * 8]);
    gl_lds16(&Vt_g[(size_t)(g * 64 + sr1) * 2048 + k0 + so1], &Vs[p1 * 8]);
    __syncthreads();

    const bool act0 = (t < ntiles - 1);   // frag0 fully masked on the last tile

    // QK^T (K-frags shared across both q-frags)
    f32x4 sc[2][4];
#pragma unroll
    for (int kt = 0; kt < 4; kt++) {
      const int krow = kt * 16 + m15;
      bf16x8 kf0 = *(const bf16x8*)&Ks[krow * 64 + (q4 ^ (krow & 7)) * 8];
      bf16x8 kf1 = *(const bf16x8*)&Ks[krow * 64 + ((q4 + 4) ^ (krow & 7)) * 8];
      sc[1][kt] = (f32x4){0.f, 0.f, 0.f, 0.f};
      sc[1][kt] = __builtin_amdgcn_mfma_f32_16x16x32_bf16(qf[1][0], kf0, sc[1][kt], 0, 0, 0);
      sc[1][kt] = __builtin_amdgcn_mfma_f32_16x16x32_bf16(qf[1][1], kf1, sc[1][kt], 0, 0, 0);
      if (act0) {
        sc[0][kt] = (f32x4){0.f, 0.f, 0.f, 0.f};
        sc[0][kt] = __builtin_amdgcn_mfma_f32_16x16x32_bf16(qf[0][0], kf0, sc[0][kt], 0, 0, 0);
        sc[0][kt] = __builtin_amdgcn_mfma_f32_16x16x32_bf16(qf[0][1], kf1, sc[0][kt], 0, 0, 0);
      }
    }

    // mask + online softmax + P pack, per frag
    bf16x8 pf[2][2];
#pragma unroll
    for (int f = 0; f < 2; f++) {
      if (f == 0 && !act0) continue;
      const int fbase = qb + f * 64 + wave * 16;
      if (k0 + 63 > fbase) {
#pragma unroll
        for (int kt = 0; kt < 4; kt++) {
          int key = k0 + kt * 16 + m15;
#pragma unroll
          for (int r = 0; r < 4; r++)
            if (key > fbase + q4 * 4 + r) sc[f][kt][r] = -1e30f;
        }
      }
#pragma unroll
      for (int r = 0; r < 4; r++) {
        float mt = fmaxf(fmaxf(sc[f][0][r], sc[f][1][r]), fmaxf(sc[f][2][r], sc[f][3][r]));
#pragma unroll
        for (int off = 1; off < 16; off <<= 1) mt = fmaxf(mt, __shfl_xor(mt, off));
        float mnew = fmaxf(m_i[f][r], mt);
        float alpha = __expf(m_i[f][r] - mnew);
        m_i[f][r] = mnew;
        float rs = 0.f;
#pragma unroll
        for (int kt = 0; kt < 4; kt++) {
          float p = __expf(sc[f][kt][r] - mnew);
          sc[f][kt][r] = p;
          rs += p;
        }
#pragma unroll
        for (int off = 1; off < 16; off <<= 1) rs += __shfl_xor(rs, off);
        l_i[f][r] = l_i[f][r] * alpha + rs;
#pragma unroll
        for (int v = 0; v < 4; v++) accO[f][v][r] *= alpha;
      }
      // C-layout -> LDS (padded stride 72) -> A-layout
#pragma unroll
      for (int kt = 0; kt < 4; kt++)
#pragma unroll
        for (int r = 0; r < 4; r++)
          Pl[wave * 1152 + (q4 * 4 + r) * 72 + kt * 16 + m15] = f2bf(sc[f][kt][r]);
      pf[f][0] = *(const bf16x8*)&Pl[wave * 1152 + m15 * 72 + q4 * 8];
      pf[f][1] = *(const bf16x8*)&Pl[wave * 1152 + m15 * 72 + 32 + q4 * 8];
    }

    // PV (V-frags shared across both q-frags)
#pragma unroll
    for (int vt = 0; vt < 4; vt++) {
      const int vrow = vt * 16 + m15;
      bf16x8 vf0 = *(const bf16x8*)&Vs[vrow * 64 + (q4 ^ (vrow & 7)) * 8];
      bf16x8 vf1 = *(const bf16x8*)&Vs[vrow * 64 + ((q4 + 4) ^ (vrow & 7)) * 8];
      accO[1][vt] = __builtin_amdgcn_mfma_f32_16x16x32_bf16(pf[1][0], vf0, accO[1][vt], 0, 0, 0);
      accO[1][vt] = __builtin_amdgcn_mfma_f32_16x16x32_bf16(pf[1][1], vf1, accO[1][vt], 0, 0, 0);
      if (act0) {
        accO[0][vt] = __builtin_amdgcn_mfma_f32_16x16x32_bf16(pf[0][0], vf0, accO[0][vt], 0, 0, 0);
        accO[0][vt] = __builtin_amdgcn_mfma_f32_16x16x32_bf16(pf[0][1], vf1, accO[0][vt], 0, 0, 0);
      }
    }
    __syncthreads();   // protect Ks/Vs before next stage
  }

  // epilogue
#pragma unroll
  for (int f = 0; f < 2; f++)
#pragma unroll
    for (int vt = 0; vt < 4; vt++)
#pragma unroll
      for (int r = 0; r < 4; r++) {
        int row = qb + f * 64 + wave * 16 + q4 * 4 + r;
        int col = h * 64 + vt * 16 + m15;
        Ob[(size_t)row * 2048 + col] = f2bf(accO[f][vt][r] / l_i[f][r]);
      }
}

extern "C" void kernel_launch(void* const* d_in, const int* in_sizes, int n_in,
                              void* d_out, int out_size, void* d_ws, size_t ws_size,
                              hipStream_t stream) {
  const float* x    = (const float*)d_in[0];
  // d_in[1] = mask: causal triu(k=1), computed analytically
  const float* cosv = (const float*)d_in[2];
  const float* sinv = (const float*)d_in[3];
  const float* Wq   = (const float*)d_in[4];
  const float* Wk   = (const float*)d_in[5];
  const float* Wv   = (const float*)d_in[6];
  const float* Wo   = (const float*)d_in[7];
  float* out = (float*)d_out;

  unsigned short* xb   = (unsigned short*)d_ws;            // 8.4 MB; later reused as attn-out Ob
  unsigned short* Wcat = xb + (size_t)2048 * 2048;         // 12.6 MB; later reused as Wo_bf
  unsigned short* QKV  = Wcat + (size_t)3072 * 2048;       // 12.6 MB (V region unused)
  unsigned short* Vt_g = QKV + (size_t)3072 * 2048;        // 2 MB: [g*64+d][s]

  dim3 blk(256);
  cvt4<<<4096, blk, 0, stream>>>(x,  xb,                            (2048 * 2048) / 4);
  cvt4<<<4096, blk, 0, stream>>>(Wq, Wcat,                          (2048 * 2048) / 4);
  cvt4<<<1024, blk, 0, stream>>>(Wk, Wcat + (size_t)2048 * 2048,    (512 * 2048) / 4);
  cvt4<<<1024, blk, 0, stream>>>(Wv, Wcat + (size_t)2560 * 2048,    (512 * 2048) / 4);
  // fused QKV projection; V cols (>=2560) written transposed into Vt_g
  gemm_bf16<<<dim3(24, 16), blk, 0, stream>>>(xb, Wcat, nullptr, QKV, Vt_g, 2048, 3072, 2048);
  cvt4<<<4096, blk, 0, stream>>>(Wo, Wcat, (2048 * 2048) / 4);
  rope_bf16<<<(2048 * 40 * 32) / 256, blk, 0, stream>>>(QKV, cosv, sinv);
  flash_mfma<<<dim3(16, 32), blk, 0, stream>>>(QKV, Vt_g, xb);
  gemm_bf16<<<dim3(16, 16), blk, 0, stream>>>(xb, Wcat, out, nullptr, nullptr, 2048, 2048, 2048);
}

// Round 5
// 265.089 us; speedup vs baseline: 8.4253x; 1.3473x over previous
//
#include <hip/hip_runtime.h>
#include <cstddef>
#include <cstdint>

#define S 2048
#define Dm 2048
#define NH 32
#define NG 8
#define HD 64

typedef __attribute__((ext_vector_type(8))) short bf16x8;
typedef __attribute__((ext_vector_type(4))) short bf16x4;
typedef __attribute__((ext_vector_type(4))) float f32x4;

__device__ __forceinline__ float fast_exp2(float x) { return __builtin_amdgcn_exp2f(x); }

__device__ __forceinline__ unsigned short f2bf(float f) {
  unsigned int u = __builtin_bit_cast(unsigned int, f);
  u = (u + 0x7fffu + ((u >> 16) & 1u)) >> 16;
  return (unsigned short)u;
}
__device__ __forceinline__ float bf2f(unsigned short h) {
  unsigned int u = ((unsigned int)h) << 16;
  return __builtin_bit_cast(float, u);
}
// pack two f32 -> (bf16 lo | bf16 hi<<16), round-to-nearest-ish
__device__ __forceinline__ unsigned int pk2bf(float lo, float hi) {
  unsigned int a = __builtin_bit_cast(unsigned int, lo) + 0x8000u;
  unsigned int b = __builtin_bit_cast(unsigned int, hi) + 0x8000u;
  return (a >> 16) | (b & 0xffff0000u);
}
// async global->LDS, 16B per lane
__device__ __forceinline__ void gl_lds16(const unsigned short* g, unsigned short* l) {
  __builtin_amdgcn_global_load_lds(
      (const __attribute__((address_space(1))) unsigned int*)g,
      (__attribute__((address_space(3))) unsigned int*)l, 16, 0, 0);
}

// ---------------- fp32 -> bf16 convert, 4 elems/thread ----------------
__global__ __launch_bounds__(256) void cvt4(const float* __restrict__ in,
                                            unsigned short* __restrict__ out,
                                            int n4) {
  int i = blockIdx.x * 256 + threadIdx.x;
  if (i >= n4) return;
  float4 v = ((const float4*)in)[i];
  ushort4 o;
  o.x = f2bf(v.x); o.y = f2bf(v.y); o.z = f2bf(v.z); o.w = f2bf(v.w);
  ((ushort4*)out)[i] = o;
}

// ---------------- bf16 MFMA GEMM: C[M,N] = A[M,K] * B[N,K]^T ----------------
// 64x128 tile (M x N), BK=32, global_load_lds staging; 4 waves of 32x64.
// Cols >= 2560 with VtOut set are written transposed to VtOut[(col-2560)*2048+row].
__global__ __launch_bounds__(256) void gemm_bf16(const unsigned short* __restrict__ A,
                                                 const unsigned short* __restrict__ B,
                                                 float* __restrict__ Cf,
                                                 unsigned short* __restrict__ Cb,
                                                 unsigned short* __restrict__ VtOut,
                                                 int M, int N, int K) {
  __shared__ __align__(16) unsigned short As[64 * 32];
  __shared__ __align__(16) unsigned short Bs[128 * 32];
  const int tid = threadIdx.x;
  const int lane = tid & 63, wave = tid >> 6;
  const int row0 = blockIdx.y * 64, col0 = blockIdx.x * 128;
  const int wr = (wave >> 1) * 32, wc = (wave & 1) * 64;

  f32x4 acc[2][4];
#pragma unroll
  for (int i = 0; i < 2; i++)
#pragma unroll
    for (int j = 0; j < 4; j++) acc[i][j] = (f32x4){0.f, 0.f, 0.f, 0.f};

  const int sr = tid >> 2, so = (tid & 3) * 8;   // A: 256 chunks; B: 512 chunks
  const int fr = lane & 15, fk = (lane >> 4) * 8;

  for (int k0 = 0; k0 < K; k0 += 32) {
    gl_lds16(&A[(size_t)(row0 + sr) * K + k0 + so], &As[tid * 8]);
    gl_lds16(&B[(size_t)(col0 + sr) * K + k0 + so], &Bs[tid * 8]);
    gl_lds16(&B[(size_t)(col0 + 64 + sr) * K + k0 + so], &Bs[(tid + 256) * 8]);
    __syncthreads();
    bf16x8 af[2], bfr[4];
#pragma unroll
    for (int i = 0; i < 2; i++) af[i]  = *(const bf16x8*)&As[(wr + i * 16 + fr) * 32 + fk];
#pragma unroll
    for (int j = 0; j < 4; j++) bfr[j] = *(const bf16x8*)&Bs[(wc + j * 16 + fr) * 32 + fk];
#pragma unroll
    for (int i = 0; i < 2; i++)
#pragma unroll
      for (int j = 0; j < 4; j++)
        acc[i][j] = __builtin_amdgcn_mfma_f32_16x16x32_bf16(af[i], bfr[j], acc[i][j], 0, 0, 0);
    __syncthreads();
  }

  const int cc = lane & 15, cr = (lane >> 4) * 4;
  const bool vmode = (VtOut != nullptr) && (col0 >= 2560);
#pragma unroll
  for (int i = 0; i < 2; i++)
#pragma unroll
    for (int j = 0; j < 4; j++) {
      int gc = col0 + wc + j * 16 + cc;
#pragma unroll
      for (int r = 0; r < 4; r++) {
        int gr = row0 + wr + i * 16 + cr + r;
        if (vmode)       VtOut[(size_t)(gc - 2560) * 2048 + gr] = f2bf(acc[i][j][r]);
        else if (Cb)     Cb[(size_t)gr * N + gc] = f2bf(acc[i][j][r]);
        else             Cf[(size_t)gr * N + gc] = acc[i][j][r];
      }
    }
}

// ---------------- RoPE in place on bf16 QKV buffer [s][3072] ----------------
// Q cols h*64 (h<32): scaled by (1/sqrt(HD))*log2(e) so attention uses exp2.
__global__ __launch_bounds__(256) void rope_bf16(unsigned short* __restrict__ QKV,
                                                 const float* __restrict__ cosv,
                                                 const float* __restrict__ sinv) {
  int i = blockIdx.x * 256 + threadIdx.x;    // over S*40*32
  int d = i & 31;
  int hh = (i >> 5) % 40;
  int s = i / (32 * 40);
  float sc = (hh < 32) ? 0.1803368801111601f : 1.0f;   // 0.125 * log2(e)
  int col = (hh < 32) ? hh * 64 : 2048 + (hh - 32) * 64;
  unsigned short* row = QKV + (size_t)s * 3072 + col;
  float c1 = cosv[s * 64 + d],      s1 = sinv[s * 64 + d];
  float c2 = cosv[s * 64 + d + 32], s2 = sinv[s * 64 + d + 32];
  float t1 = bf2f(row[d]), t2 = bf2f(row[d + 32]);
  row[d]      = f2bf((t1 * c1 - t2 * s1) * sc);
  row[d + 32] = f2bf((t2 * c2 + t1 * s2) * sc);
}

// ---------------- MFMA causal GQA flash attention (transposed scores) ----------------
// 1024 blocks 1-D; block L: head = L&31, u = L>>5 -> qt via sum-invariant map.
// Block covers q rows [qt*64, qt*64+64); wave w owns rows qt*64 + w*16 + (0..15).
// Scores via mfma(K, Q): D col = q (lane&15), row = key (q4*4+reg).
// P stays in registers as the PV A-operand (permuted contraction indexing).
__global__ __launch_bounds__(256, 4) void flash_mfma(const unsigned short* __restrict__ QKV,
                                                     const unsigned short* __restrict__ Vt_g,
                                                     unsigned short* __restrict__ Ob) {
  __shared__ __align__(16) unsigned short Ks[64 * 64];
  __shared__ __align__(16) unsigned short Vs[64 * 64];

  const int tid = threadIdx.x;
  const int lane = tid & 63, wave = tid >> 6;
  const int m15 = lane & 15, q4 = lane >> 4;

  const int L = blockIdx.x;
  const int h = L & 31, g = h >> 2;
  const int u = L >> 5, a = u >> 3, bq = u & 7;
  const int qt = (a == 0) ? 31 - bq : (a == 1) ? bq : (a == 2) ? 23 - bq : 8 + bq;

  // Q fragment (B-operand): B[n=q][k=d]; lane (m15,q4) holds row qt*64+wave*16+m15, d=q4*8+j
  const size_t qrow = (size_t)(qt * 64 + wave * 16 + m15) * 3072 + h * 64;
  const bf16x8 qf0 = *(const bf16x8*)&QKV[qrow + q4 * 8];
  const bf16x8 qf1 = *(const bf16x8*)&QKV[qrow + 32 + q4 * 8];

  f32x4 accO[4];
#pragma unroll
  for (int v = 0; v < 4; v++) accO[v] = (f32x4){0.f, 0.f, 0.f, 0.f};
  float m_i = -1e30f, l_i = 0.f;

  // staging: 512 chunks of 16B per matrix; p -> row p>>3, swizzled chunk (p&7)^(row&7)
  const int p0 = wave * 128 + lane, p1 = p0 + 64;
  const int sr0 = p0 >> 3, so0 = ((p0 & 7) ^ (sr0 & 7)) * 8;
  const int sr1 = p1 >> 3, so1 = ((p1 & 7) ^ (sr1 & 7)) * 8;

  const int ntiles = qt + 1;
  for (int t = 0; t < ntiles; t++) {
    const int k0 = t * 64;
    gl_lds16(&QKV[(size_t)(k0 + sr0) * 3072 + 2048 + g * 64 + so0], &Ks[p0 * 8]);
    gl_lds16(&QKV[(size_t)(k0 + sr1) * 3072 + 2048 + g * 64 + so1], &Ks[p1 * 8]);
    gl_lds16(&Vt_g[(size_t)(g * 64 + sr0) * 2048 + k0 + so0], &Vs[p0 * 8]);
    gl_lds16(&Vt_g[(size_t)(g * 64 + sr1) * 2048 + k0 + so1], &Vs[p1 * 8]);
    __syncthreads();

    // K^T Q: sc[kt] D[m=key=kt*16+q4*4+r][n=q=m15]
    f32x4 sc[4];
#pragma unroll
    for (int kt = 0; kt < 4; kt++) {
      const int krow = kt * 16 + m15;
      bf16x8 kf0 = *(const bf16x8*)&Ks[krow * 64 + (q4 ^ (krow & 7)) * 8];
      bf16x8 kf1 = *(const bf16x8*)&Ks[krow * 64 + ((q4 + 4) ^ (krow & 7)) * 8];
      f32x4 z = (f32x4){0.f, 0.f, 0.f, 0.f};
      z = __builtin_amdgcn_mfma_f32_16x16x32_bf16(kf0, qf0, z, 0, 0, 0);
      sc[kt] = __builtin_amdgcn_mfma_f32_16x16x32_bf16(kf1, qf1, z, 0, 0, 0);
    }

    // causal mask on the diagonal tile: key offset kt*16+q4*4+r vs q offset wave*16+m15
    if (t == qt) {
      const int qo = wave * 16 + m15;
#pragma unroll
      for (int kt = 0; kt < 4; kt++)
#pragma unroll
        for (int r = 0; r < 4; r++)
          if (kt * 16 + q4 * 4 + r > qo) sc[kt][r] = -1e30f;
    }

    // online softmax (per q = m15, vectorized across lanes; log2 domain)
    float mt = sc[0][0];
#pragma unroll
    for (int kt = 0; kt < 4; kt++)
#pragma unroll
      for (int r = 0; r < 4; r++) mt = fmaxf(mt, sc[kt][r]);
    mt = fmaxf(mt, __shfl_xor(mt, 16));
    mt = fmaxf(mt, __shfl_xor(mt, 32));
    const float mnew = fmaxf(m_i, mt);
    const float alpha = fast_exp2(m_i - mnew);
    m_i = mnew;
    float rs = 0.f;
#pragma unroll
    for (int kt = 0; kt < 4; kt++)
#pragma unroll
      for (int r = 0; r < 4; r++) {
        float p = fast_exp2(sc[kt][r] - mnew);
        sc[kt][r] = p;
        rs += p;
      }
    rs += __shfl_xor(rs, 16);
    rs += __shfl_xor(rs, 32);
    l_i = l_i * alpha + rs;

    // broadcast alpha for accO rows (row r <-> q = q4*4+r, held at lane 20*q4+r)
    float ar[4];
#pragma unroll
    for (int r = 0; r < 4; r++) ar[r] = __shfl(alpha, q4 * 20 + r);
#pragma unroll
    for (int v = 0; v < 4; v++)
#pragma unroll
      for (int r = 0; r < 4; r++) accO[v][r] *= ar[r];

    // pack P into PV A-operands: pA0 keys {q4*4+j, 16+q4*4+j}, pA1 keys {32+.., 48+..}
    int4 pa0, pa1;
    pa0.x = pk2bf(sc[0][0], sc[0][1]); pa0.y = pk2bf(sc[0][2], sc[0][3]);
    pa0.z = pk2bf(sc[1][0], sc[1][1]); pa0.w = pk2bf(sc[1][2], sc[1][3]);
    pa1.x = pk2bf(sc[2][0], sc[2][1]); pa1.y = pk2bf(sc[2][2], sc[2][3]);
    pa1.z = pk2bf(sc[3][0], sc[3][1]); pa1.w = pk2bf(sc[3][2], sc[3][3]);
    const bf16x8 pA0 = __builtin_bit_cast(bf16x8, pa0);
    const bf16x8 pA1 = __builtin_bit_cast(bf16x8, pa1);

    // PV: accO[vt] (D[m=q][n=d]) += P * V ; V B-operand matches permuted key slots
#pragma unroll
    for (int vt = 0; vt < 4; vt++) {
      const int vrow = vt * 16 + m15;
      const int base = vrow * 64, sw = vrow & 7, half = (q4 & 1) * 4, c1 = q4 >> 1;
      bf16x4 w00 = *(const bf16x4*)&Vs[base + (c1 ^ sw) * 8 + half];
      bf16x4 w01 = *(const bf16x4*)&Vs[base + ((c1 + 2) ^ sw) * 8 + half];
      bf16x4 w10 = *(const bf16x4*)&Vs[base + ((c1 + 4) ^ sw) * 8 + half];
      bf16x4 w11 = *(const bf16x4*)&Vs[base + ((c1 + 6) ^ sw) * 8 + half];
      bf16x8 vB0 = __builtin_shufflevector(w00, w01, 0, 1, 2, 3, 4, 5, 6, 7);
      bf16x8 vB1 = __builtin_shufflevector(w10, w11, 0, 1, 2, 3, 4, 5, 6, 7);
      accO[vt] = __builtin_amdgcn_mfma_f32_16x16x32_bf16(pA0, vB0, accO[vt], 0, 0, 0);
      accO[vt] = __builtin_amdgcn_mfma_f32_16x16x32_bf16(pA1, vB1, accO[vt], 0, 0, 0);
    }
    __syncthreads();   // protect Ks/Vs before next restage
  }

  // epilogue: rows = qt*64 + wave*16 + q4*4 + r, col = h*64 + vt*16 + m15
  float lr[4];
#pragma unroll
  for (int r = 0; r < 4; r++) lr[r] = 1.0f / __shfl(l_i, q4 * 20 + r);
#pragma unroll
  for (int vt = 0; vt < 4; vt++)
#pragma unroll
    for (int r = 0; r < 4; r++) {
      int row = qt * 64 + wave * 16 + q4 * 4 + r;
      Ob[(size_t)row * 2048 + h * 64 + vt * 16 + m15] = f2bf(accO[vt][r] * lr[r]);
    }
}

extern "C" void kernel_launch(void* const* d_in, const int* in_sizes, int n_in,
                              void* d_out, int out_size, void* d_ws, size_t ws_size,
                              hipStream_t stream) {
  const float* x    = (const float*)d_in[0];
  // d_in[1] = mask: causal triu(k=1), computed analytically
  const float* cosv = (const float*)d_in[2];
  const float* sinv = (const float*)d_in[3];
  const float* Wq   = (const float*)d_in[4];
  const float* Wk   = (const float*)d_in[5];
  const float* Wv   = (const float*)d_in[6];
  const float* Wo   = (const float*)d_in[7];
  float* out = (float*)d_out;

  unsigned short* xb   = (unsigned short*)d_ws;            // 8.4 MB; later reused as attn-out Ob
  unsigned short* Wcat = xb + (size_t)2048 * 2048;         // 12.6 MB; later reused as Wo_bf
  unsigned short* QKV  = Wcat + (size_t)3072 * 2048;       // 12.6 MB (V cols unused)
  unsigned short* Vt_g = QKV + (size_t)3072 * 2048;        // 2 MB: [g*64+d][s]

  dim3 blk(256);
  cvt4<<<4096, blk, 0, stream>>>(x,  xb,                            (2048 * 2048) / 4);
  cvt4<<<4096, blk, 0, stream>>>(Wq, Wcat,                          (2048 * 2048) / 4);
  cvt4<<<1024, blk, 0, stream>>>(Wk, Wcat + (size_t)2048 * 2048,    (512 * 2048) / 4);
  cvt4<<<1024, blk, 0, stream>>>(Wv, Wcat + (size_t)2560 * 2048,    (512 * 2048) / 4);
  // fused QKV projection; V cols (>=2560) written transposed into Vt_g
  gemm_bf16<<<dim3(24, 32), blk, 0, stream>>>(xb, Wcat, nullptr, QKV, Vt_g, 2048, 3072, 2048);
  cvt4<<<4096, blk, 0, stream>>>(Wo, Wcat, (2048 * 2048) / 4);
  rope_bf16<<<(2048 * 40 * 32) / 256, blk, 0, stream>>>(QKV, cosv, sinv);
  flash_mfma<<<1024, blk, 0, stream>>>(QKV, Vt_g, xb);
  gemm_bf16<<<dim3(16, 32), blk, 0, stream>>>(xb, Wcat, out, nullptr, nullptr, 2048, 2048, 2048);
}

// Round 6
// 232.838 us; speedup vs baseline: 9.5923x; 1.1385x over previous
//
#include <hip/hip_runtime.h>
#include <cstddef>
#include <cstdint>

#define S 2048
#define Dm 2048
#define NH 32
#define NG 8
#define HD 64

typedef __attribute__((ext_vector_type(8))) short bf16x8;
typedef __attribute__((ext_vector_type(4))) short bf16x4;
typedef __attribute__((ext_vector_type(4))) float f32x4;

__device__ __forceinline__ float fast_exp2(float x) { return __builtin_amdgcn_exp2f(x); }

__device__ __forceinline__ unsigned short f2bf(float f) {
  unsigned int u = __builtin_bit_cast(unsigned int, f);
  u = (u + 0x7fffu + ((u >> 16) & 1u)) >> 16;
  return (unsigned short)u;
}
__device__ __forceinline__ float bf2f(unsigned short h) {
  unsigned int u = ((unsigned int)h) << 16;
  return __builtin_bit_cast(float, u);
}
// pack two f32 -> (bf16 lo | bf16 hi<<16)
__device__ __forceinline__ unsigned int pk2bf(float lo, float hi) {
  unsigned int a = __builtin_bit_cast(unsigned int, lo) + 0x8000u;
  unsigned int b = __builtin_bit_cast(unsigned int, hi) + 0x8000u;
  return (a >> 16) | (b & 0xffff0000u);
}
// async global->LDS, 16B per lane
__device__ __forceinline__ void gl_lds16(const unsigned short* g, unsigned short* l) {
  __builtin_amdgcn_global_load_lds(
      (const __attribute__((address_space(1))) unsigned int*)g,
      (__attribute__((address_space(3))) unsigned int*)l, 16, 0, 0);
}

#define QSC 0.1803368801111601f   // 0.125 * log2(e): fold 1/sqrt(HD) and exp2 conversion into Q

// ---------------- fused fp32 -> bf16 convert for all 5 inputs ----------------
// float4-group ranges: x[0,1048576) Wq[..2097152) Wk[..2359296) Wv[..2621440) Wo[..3670016)
__global__ __launch_bounds__(256) void cvt_all(const float* __restrict__ x,
                                               const float* __restrict__ Wq,
                                               const float* __restrict__ Wk,
                                               const float* __restrict__ Wv,
                                               const float* __restrict__ Wo,
                                               unsigned short* __restrict__ xb,
                                               unsigned short* __restrict__ Wcat,
                                               unsigned short* __restrict__ Wob) {
  int i = blockIdx.x * 256 + threadIdx.x;
  const float4* src;
  ushort4* dst;
  if (i < 1048576)      { src = (const float4*)x  + i;             dst = (ushort4*)xb + i; }
  else if (i < 2097152) { src = (const float4*)Wq + (i - 1048576); dst = (ushort4*)Wcat + (i - 1048576); }
  else if (i < 2359296) { src = (const float4*)Wk + (i - 2097152); dst = (ushort4*)Wcat + 1048576 + (i - 2097152); }
  else if (i < 2621440) { src = (const float4*)Wv + (i - 2359296); dst = (ushort4*)Wcat + 1310720 + (i - 2359296); }
  else                  { src = (const float4*)Wo + (i - 2621440); dst = (ushort4*)Wob + (i - 2621440); }
  float4 v = *src;
  ushort4 o;
  o.x = f2bf(v.x); o.y = f2bf(v.y); o.z = f2bf(v.z); o.w = f2bf(v.w);
  *dst = o;
}

// ---------------- bf16 MFMA GEMM: C[M,N] = A[M,K] * B[N,K]^T ----------------
// 64x128 tile, BK=64, XOR-swizzled LDS (conflict-free b128 frag reads), 4 waves of 32x64.
// cosv != nullptr => QKV mode: fused RoPE (+Q scale) on cols <2560, transpose-V for cols >=2560.
__global__ __launch_bounds__(256) void gemm_bf16(const unsigned short* __restrict__ A,
                                                 const unsigned short* __restrict__ B,
                                                 float* __restrict__ Cf,
                                                 unsigned short* __restrict__ Cb,
                                                 unsigned short* __restrict__ VtOut,
                                                 const float* __restrict__ cosv,
                                                 const float* __restrict__ sinv,
                                                 int M, int N, int K) {
  __shared__ __align__(16) unsigned short As[64 * 64];    // 8 KB
  __shared__ __align__(16) unsigned short Bs[128 * 64];   // 16 KB
  const int tid = threadIdx.x;
  const int lane = tid & 63, wave = tid >> 6;
  const int row0 = blockIdx.y * 64, col0 = blockIdx.x * 128;
  const int wr = (wave >> 1) * 32, wc = (wave & 1) * 64;

  f32x4 acc[2][4];
#pragma unroll
  for (int i = 0; i < 2; i++)
#pragma unroll
    for (int j = 0; j < 4; j++) acc[i][j] = (f32x4){0.f, 0.f, 0.f, 0.f};

  // staging: chunk p -> row p>>3, phys slot p&7 holds global chunk (p&7)^(row&7)
  const int arow0 = tid >> 3, aslot0 = ((tid & 7) ^ (arow0 & 7)) * 8;         // A chunk tid
  const int arow1 = (tid + 256) >> 3, aslot1 = (((tid + 256) & 7) ^ (arow1 & 7)) * 8;
  const int fr = lane & 15, q4 = lane >> 4;

  for (int k0 = 0; k0 < K; k0 += 64) {
    // A: 512 chunks (64 rows x 8), 2 per thread
    gl_lds16(&A[(size_t)(row0 + arow0) * K + k0 + aslot0], &As[tid * 8]);
    gl_lds16(&A[(size_t)(row0 + arow1) * K + k0 + aslot1], &As[(tid + 256) * 8]);
    // B: 1024 chunks (128 rows x 8), 4 per thread
#pragma unroll
    for (int b = 0; b < 4; b++) {
      int p = tid + b * 256;
      int r = p >> 3, sl = ((p & 7) ^ (r & 7)) * 8;
      gl_lds16(&B[(size_t)(col0 + r) * K + k0 + sl], &Bs[p * 8]);
    }
    __syncthreads();
#pragma unroll
    for (int kk = 0; kk < 2; kk++) {
      bf16x8 af[2], bfr[4];
#pragma unroll
      for (int i = 0; i < 2; i++) {
        int R = wr + i * 16 + fr;
        af[i] = *(const bf16x8*)&As[R * 64 + ((q4 + kk * 4) ^ (R & 7)) * 8];
      }
#pragma unroll
      for (int j = 0; j < 4; j++) {
        int R = wc + j * 16 + fr;
        bfr[j] = *(const bf16x8*)&Bs[R * 64 + ((q4 + kk * 4) ^ (R & 7)) * 8];
      }
#pragma unroll
      for (int i = 0; i < 2; i++)
#pragma unroll
        for (int j = 0; j < 4; j++)
          acc[i][j] = __builtin_amdgcn_mfma_f32_16x16x32_bf16(af[i], bfr[j], acc[i][j], 0, 0, 0);
    }
    __syncthreads();
  }

  const int cc = lane & 15, cr = (lane >> 4) * 4;

  if (cosv) {
    // fused RoPE: pair slots (j, j+2) hold dims d, d+32 of the same head (cos[d+32]==cos[d])
#pragma unroll
    for (int i = 0; i < 2; i++) {
      int grb = row0 + wr + i * 16 + cr;
#pragma unroll
      for (int j = 0; j < 2; j++) {
        int gc = col0 + wc + j * 16 + cc;
        if (gc < 2560) {
          int d = j * 16 + cc;               // (col0+wc) is 64-aligned
          float qs = (gc < 2048) ? QSC : 1.0f;
#pragma unroll
          for (int r = 0; r < 4; r++) {
            float c = cosv[(grb + r) * 64 + d];
            float s = sinv[(grb + r) * 64 + d];
            float t1 = acc[i][j][r], t2 = acc[i][j + 2][r];
            acc[i][j][r]     = (t1 * c - t2 * s) * qs;
            acc[i][j + 2][r] = (t2 * c + t1 * s) * qs;
          }
        }
      }
    }
  }

#pragma unroll
  for (int i = 0; i < 2; i++)
#pragma unroll
    for (int j = 0; j < 4; j++) {
      int gc = col0 + wc + j * 16 + cc;
#pragma unroll
      for (int r = 0; r < 4; r++) {
        int gr = row0 + wr + i * 16 + cr + r;
        if (cosv) {
          if (gc >= 2560) VtOut[(size_t)(gc - 2560) * 2048 + gr] = f2bf(acc[i][j][r]);
          else            Cb[(size_t)gr * N + gc] = f2bf(acc[i][j][r]);
        } else if (Cf)    Cf[(size_t)gr * N + gc] = acc[i][j][r];
        else              Cb[(size_t)gr * N + gc] = f2bf(acc[i][j][r]);
      }
    }
}

// ---------------- MFMA causal GQA flash attention (transposed scores) ----------------
// 1024 blocks 1-D; block L: head = L&31, u = L>>5 -> qt via sum-invariant map.
// Scores via mfma(K, Q): D col = q (lane&15), row = key (q4*4+reg). P stays in registers.
__global__ __launch_bounds__(256, 4) void flash_mfma(const unsigned short* __restrict__ QKV,
                                                     const unsigned short* __restrict__ Vt_g,
                                                     unsigned short* __restrict__ Ob) {
  __shared__ __align__(16) unsigned short Ks[64 * 64];
  __shared__ __align__(16) unsigned short Vs[64 * 64];

  const int tid = threadIdx.x;
  const int lane = tid & 63, wave = tid >> 6;
  const int m15 = lane & 15, q4 = lane >> 4;

  const int L = blockIdx.x;
  const int h = L & 31, g = h >> 2;
  const int u = L >> 5, a = u >> 3, bq = u & 7;
  const int qt = (a == 0) ? 31 - bq : (a == 1) ? bq : (a == 2) ? 23 - bq : 8 + bq;

  const size_t qrow = (size_t)(qt * 64 + wave * 16 + m15) * 3072 + h * 64;
  const bf16x8 qf0 = *(const bf16x8*)&QKV[qrow + q4 * 8];
  const bf16x8 qf1 = *(const bf16x8*)&QKV[qrow + 32 + q4 * 8];

  f32x4 accO[4];
#pragma unroll
  for (int v = 0; v < 4; v++) accO[v] = (f32x4){0.f, 0.f, 0.f, 0.f};
  float m_i = -1e30f, l_i = 0.f;

  const int p0 = wave * 128 + lane, p1 = p0 + 64;
  const int sr0 = p0 >> 3, so0 = ((p0 & 7) ^ (sr0 & 7)) * 8;
  const int sr1 = p1 >> 3, so1 = ((p1 & 7) ^ (sr1 & 7)) * 8;

  const int ntiles = qt + 1;
  for (int t = 0; t < ntiles; t++) {
    const int k0 = t * 64;
    gl_lds16(&QKV[(size_t)(k0 + sr0) * 3072 + 2048 + g * 64 + so0], &Ks[p0 * 8]);
    gl_lds16(&QKV[(size_t)(k0 + sr1) * 3072 + 2048 + g * 64 + so1], &Ks[p1 * 8]);
    gl_lds16(&Vt_g[(size_t)(g * 64 + sr0) * 2048 + k0 + so0], &Vs[p0 * 8]);
    gl_lds16(&Vt_g[(size_t)(g * 64 + sr1) * 2048 + k0 + so1], &Vs[p1 * 8]);
    __syncthreads();

    f32x4 sc[4];
#pragma unroll
    for (int kt = 0; kt < 4; kt++) {
      const int krow = kt * 16 + m15;
      bf16x8 kf0 = *(const bf16x8*)&Ks[krow * 64 + (q4 ^ (krow & 7)) * 8];
      bf16x8 kf1 = *(const bf16x8*)&Ks[krow * 64 + ((q4 + 4) ^ (krow & 7)) * 8];
      f32x4 z = (f32x4){0.f, 0.f, 0.f, 0.f};
      z = __builtin_amdgcn_mfma_f32_16x16x32_bf16(kf0, qf0, z, 0, 0, 0);
      sc[kt] = __builtin_amdgcn_mfma_f32_16x16x32_bf16(kf1, qf1, z, 0, 0, 0);
    }

    if (t == qt) {
      const int qo = wave * 16 + m15;
#pragma unroll
      for (int kt = 0; kt < 4; kt++)
#pragma unroll
        for (int r = 0; r < 4; r++)
          if (kt * 16 + q4 * 4 + r > qo) sc[kt][r] = -1e30f;
    }

    float mt = sc[0][0];
#pragma unroll
    for (int kt = 0; kt < 4; kt++)
#pragma unroll
      for (int r = 0; r < 4; r++) mt = fmaxf(mt, sc[kt][r]);
    mt = fmaxf(mt, __shfl_xor(mt, 16));
    mt = fmaxf(mt, __shfl_xor(mt, 32));
    const float mnew = fmaxf(m_i, mt);
    const float alpha = fast_exp2(m_i - mnew);
    m_i = mnew;
    float rs = 0.f;
#pragma unroll
    for (int kt = 0; kt < 4; kt++)
#pragma unroll
      for (int r = 0; r < 4; r++) {
        float p = fast_exp2(sc[kt][r] - mnew);
        sc[kt][r] = p;
        rs += p;
      }
    rs += __shfl_xor(rs, 16);
    rs += __shfl_xor(rs, 32);
    l_i = l_i * alpha + rs;

    float ar[4];
#pragma unroll
    for (int r = 0; r < 4; r++) ar[r] = __shfl(alpha, q4 * 20 + r);
#pragma unroll
    for (int v = 0; v < 4; v++)
#pragma unroll
      for (int r = 0; r < 4; r++) accO[v][r] *= ar[r];

    int4 pa0, pa1;
    pa0.x = pk2bf(sc[0][0], sc[0][1]); pa0.y = pk2bf(sc[0][2], sc[0][3]);
    pa0.z = pk2bf(sc[1][0], sc[1][1]); pa0.w = pk2bf(sc[1][2], sc[1][3]);
    pa1.x = pk2bf(sc[2][0], sc[2][1]); pa1.y = pk2bf(sc[2][2], sc[2][3]);
    pa1.z = pk2bf(sc[3][0], sc[3][1]); pa1.w = pk2bf(sc[3][2], sc[3][3]);
    const bf16x8 pA0 = __builtin_bit_cast(bf16x8, pa0);
    const bf16x8 pA1 = __builtin_bit_cast(bf16x8, pa1);

#pragma unroll
    for (int vt = 0; vt < 4; vt++) {
      const int vrow = vt * 16 + m15;
      const int base = vrow * 64, sw = vrow & 7, half = (q4 & 1) * 4, c1 = q4 >> 1;
      bf16x4 w00 = *(const bf16x4*)&Vs[base + (c1 ^ sw) * 8 + half];
      bf16x4 w01 = *(const bf16x4*)&Vs[base + ((c1 + 2) ^ sw) * 8 + half];
      bf16x4 w10 = *(const bf16x4*)&Vs[base + ((c1 + 4) ^ sw) * 8 + half];
      bf16x4 w11 = *(const bf16x4*)&Vs[base + ((c1 + 6) ^ sw) * 8 + half];
      bf16x8 vB0 = __builtin_shufflevector(w00, w01, 0, 1, 2, 3, 4, 5, 6, 7);
      bf16x8 vB1 = __builtin_shufflevector(w10, w11, 0, 1, 2, 3, 4, 5, 6, 7);
      accO[vt] = __builtin_amdgcn_mfma_f32_16x16x32_bf16(pA0, vB0, accO[vt], 0, 0, 0);
      accO[vt] = __builtin_amdgcn_mfma_f32_16x16x32_bf16(pA1, vB1, accO[vt], 0, 0, 0);
    }
    __syncthreads();
  }

  float lr[4];
#pragma unroll
  for (int r = 0; r < 4; r++) lr[r] = 1.0f / __shfl(l_i, q4 * 20 + r);
#pragma unroll
  for (int vt = 0; vt < 4; vt++)
#pragma unroll
    for (int r = 0; r < 4; r++) {
      int row = qt * 64 + wave * 16 + q4 * 4 + r;
      Ob[(size_t)row * 2048 + h * 64 + vt * 16 + m15] = f2bf(accO[vt][r] * lr[r]);
    }
}

extern "C" void kernel_launch(void* const* d_in, const int* in_sizes, int n_in,
                              void* d_out, int out_size, void* d_ws, size_t ws_size,
                              hipStream_t stream) {
  const float* x    = (const float*)d_in[0];
  // d_in[1] = mask: causal triu(k=1), computed analytically
  const float* cosv = (const float*)d_in[2];
  const float* sinv = (const float*)d_in[3];
  const float* Wq   = (const float*)d_in[4];
  const float* Wk   = (const float*)d_in[5];
  const float* Wv   = (const float*)d_in[6];
  const float* Wo   = (const float*)d_in[7];
  float* out = (float*)d_out;

  unsigned short* xb   = (unsigned short*)d_ws;            // 8.4 MB; reused as attn-out Ob
  unsigned short* Wcat = xb + (size_t)2048 * 2048;         // 12.6 MB (Wq|Wk|Wv)
  unsigned short* Wob  = Wcat + (size_t)3072 * 2048;       // 8.4 MB
  unsigned short* QKV  = Wob + (size_t)2048 * 2048;        // 12.6 MB (V cols unused)
  unsigned short* Vt_g = QKV + (size_t)3072 * 2048;        // 2 MB: [g*64+d][s]   total 44 MB

  dim3 blk(256);
  cvt_all<<<14336, blk, 0, stream>>>(x, Wq, Wk, Wv, Wo, xb, Wcat, Wob);
  // fused QKV projection + RoPE (+Q scale); V cols written transposed into Vt_g
  gemm_bf16<<<dim3(24, 32), blk, 0, stream>>>(xb, Wcat, nullptr, QKV, Vt_g, cosv, sinv, 2048, 3072, 2048);
  flash_mfma<<<1024, blk, 0, stream>>>(QKV, Vt_g, xb);
  gemm_bf16<<<dim3(16, 32), blk, 0, stream>>>(xb, Wob, out, nullptr, nullptr, nullptr, nullptr, 2048, 2048, 2048);
}